// Round 2
// baseline (301.557 us; speedup 1.0000x reference)
//
#include <hip/hip_runtime.h>

// PoseCost: SE(3) log-map pose error over N = B*H poses.
// in:  pos [N,3] f32, rot [N,9] f32 (row-major 3x3), goal_pos [3], goal_rot [9], vec_weight [6]
// out: cost [N], rot_err [N], pos_err [N], v [N,3], omega [N,3]  (concat flat, f32)

#define BLOCK 256

// native clang vector: accepted by __builtin_nontemporal_store (HIP float4 is not)
typedef float f32x4 __attribute__((ext_vector_type(4)));

__global__ __launch_bounds__(BLOCK) void pose_cost_kernel(
    const float* __restrict__ pos,
    const float* __restrict__ rot,
    const float* __restrict__ gpos,
    const float* __restrict__ grot,
    const float* __restrict__ wvec,
    float* __restrict__ out,
    int N)
{
    __shared__ float sR[BLOCK * 9];   // staging: R tiles in, then reused for v/omega out
    __shared__ float sP[BLOCK * 3];

    const int t = threadIdx.x;
    const int base = blockIdx.x * BLOCK;
    const bool fullBlock = (base + BLOCK) <= N;
    const bool vecOut = fullBlock && ((N & 3) == 0);  // 16B alignment of out+3N / out+6N

    // ---- Stage inputs: coalesced 16B loads into LDS (verbatim linear copy) ----
    if (fullBlock) {
        // rot tile = 9*BLOCK floats = 576 vec4 ; pos tile = 3*BLOCK floats = 192 vec4
        // total 768 vec4 = 3 per thread, perfectly balanced.
        const f32x4* rs = reinterpret_cast<const f32x4*>(rot + (size_t)base * 9);
        const f32x4* ps = reinterpret_cast<const f32x4*>(pos + (size_t)base * 3);
        f32x4* sR4 = reinterpret_cast<f32x4*>(sR);
        f32x4* sP4 = reinterpret_cast<f32x4*>(sP);
        #pragma unroll
        for (int k = 0; k < 3; ++k) {
            const int i = k * BLOCK + t;
            if (i < (9 * BLOCK) / 4) sR4[i] = rs[i];
            else                     sP4[i - (9 * BLOCK) / 4] = ps[i - (9 * BLOCK) / 4];
        }
    } else {
        const float* rsrc = rot + (size_t)base * 9;
        const float* psrc = pos + (size_t)base * 3;
        const int rem = N - base;                 // < BLOCK
        #pragma unroll
        for (int k = 0; k < 9; ++k) {
            int i = k * BLOCK + t;
            if (i < rem * 9) sR[i] = rsrc[i];
        }
        #pragma unroll
        for (int k = 0; k < 3; ++k) {
            int i = k * BLOCK + t;
            if (i < rem * 3) sP[i] = psrc[i];
        }
    }

    // uniform (wave-invariant) goal / weight data -> scalar loads
    float G[9], g0, g1, g2, w[6];
    #pragma unroll
    for (int k = 0; k < 9; ++k) G[k] = grot[k];
    g0 = gpos[0]; g1 = gpos[1]; g2 = gpos[2];
    #pragma unroll
    for (int k = 0; k < 6; ++k) w[k] = wvec[k];

    __syncthreads();

    const int idx = base + t;
    const bool active = idx < N;

    float v0 = 0.f, v1 = 0.f, v2 = 0.f, o0 = 0.f, o1 = 0.f, o2 = 0.f;

    if (active) {
        float R[9];
        #pragma unroll
        for (int k = 0; k < 9; ++k) R[k] = sR[t * 9 + k];
        const float p0 = sP[t * 3 + 0];
        const float p1 = sP[t * 3 + 1];
        const float p2 = sP[t * 3 + 2];

        // d = goal_pos - p ;  t_ge = R^T d
        const float d0 = g0 - p0, d1 = g1 - p1, d2 = g2 - p2;
        const float tq0 = R[0] * d0 + R[3] * d1 + R[6] * d2;
        const float tq1 = R[1] * d0 + R[4] * d1 + R[7] * d2;
        const float tq2 = R[2] * d0 + R[5] * d1 + R[8] * d2;

        // M = R^T * G   (M[i][j] = sum_k R[k][i] * G[k][j])
        float M[9];
        #pragma unroll
        for (int i = 0; i < 3; ++i) {
            #pragma unroll
            for (int j = 0; j < 3; ++j) {
                M[i * 3 + j] = R[0 + i] * G[0 + j] + R[3 + i] * G[3 + j] + R[6 + i] * G[6 + j];
            }
        }

        const float tr = M[0] + M[4] + M[8];
        float cos_t = (tr - 1.0f) * 0.5f;
        cos_t = fminf(fmaxf(cos_t, -1.0f + 1e-7f), 1.0f - 1e-7f);
        const float theta = acosf(cos_t);
        // sin(acos(c)) == sqrt(1 - c^2) exactly on (0, pi); fmaf avoids cancellation
        // at the clamp boundary (1 - c*c computed with a single rounding).
        const float sin_t = sqrtf(fmaf(-cos_t, cos_t, 1.0f));

        // vee(M - M^T)/2
        const float wv0 = 0.5f * (M[7] - M[5]);
        const float wv1 = 0.5f * (M[2] - M[6]);
        const float wv2 = 0.5f * (M[3] - M[1]);

        const bool small = theta < 1e-4f;   // dead after clamp (theta >= ~4.5e-4) but keeps ref semantics
        const float th2 = theta * theta;
        const float scale = small ? (1.0f + th2 * (1.0f / 6.0f)) : (theta / sin_t);
        o0 = scale * wv0; o1 = scale * wv1; o2 = scale * wv2;

        // A = (1 - theta*sin/(2(1-cos)))/theta^2  ==  (1 - 0.5*scale*(1+cos))/theta^2
        // (identity: sin^2 = (1-cos)(1+cos)  =>  sin/(1-cos) = (1+cos)/sin)
        const float A = small ? (1.0f / 12.0f)
                              : (1.0f - 0.5f * scale * (1.0f + cos_t)) / th2;

        // v = Vinv t = t - 0.5*(omega x t) + A*(omega*(omega.t) - |omega|^2 * t)
        const float cx0 = o1 * tq2 - o2 * tq1;
        const float cx1 = o2 * tq0 - o0 * tq2;
        const float cx2 = o0 * tq1 - o1 * tq0;
        const float odt = o0 * tq0 + o1 * tq1 + o2 * tq2;
        const float on2 = o0 * o0 + o1 * o1 + o2 * o2;
        v0 = tq0 - 0.5f * cx0 + A * (o0 * odt - on2 * tq0);
        v1 = tq1 - 0.5f * cx1 + A * (o1 * odt - on2 * tq1);
        v2 = tq2 - 0.5f * cx2 + A * (o2 * odt - on2 * tq2);

        const float we0 = w[0] * o0, we1 = w[1] * o1, we2 = w[2] * o2;
        const float wp0 = w[3] * v0, wp1 = w[4] * v1, wp2 = w[5] * v2;
        float re = we0 * we0 + we1 * we1 + we2 * we2;
        float pe = wp0 * wp0 + wp1 * wp1 + wp2 * wp2;
        // CONV_ROT = CONV_TRANS = 0.0 : where(err < 0, 0, err) — keep exact semantics
        re = (re < 0.0f) ? 0.0f : re;
        pe = (pe < 0.0f) ? 0.0f : pe;
        const float cost = 15.0f * re + 100.0f * pe;

        // naturally coalesced scalar outputs; non-temporal: write-once data,
        // keep L2/L3 capacity for the input set.
        __builtin_nontemporal_store(cost, out + idx);
        __builtin_nontemporal_store(re, out + (size_t)N + idx);
        __builtin_nontemporal_store(pe, out + 2 * (size_t)N + idx);
    }

    // ---- Stage v/omega through LDS so the [N,3] stores are coalesced ----
    __syncthreads();   // all reads of sR done; safe to reuse
    if (active) {
        sR[t * 3 + 0] = v0;
        sR[t * 3 + 1] = v1;
        sR[t * 3 + 2] = v2;
        sR[BLOCK * 3 + t * 3 + 0] = o0;
        sR[BLOCK * 3 + t * 3 + 1] = o1;
        sR[BLOCK * 3 + t * 3 + 2] = o2;
    }
    __syncthreads();

    if (vecOut) {
        // v region = 192 vec4, omega region = 192 vec4 -> 384 total, <=2 per thread
        f32x4* vd = reinterpret_cast<f32x4*>(out + 3 * (size_t)N + (size_t)base * 3);
        f32x4* od = reinterpret_cast<f32x4*>(out + 6 * (size_t)N + (size_t)base * 3);
        const f32x4* s4 = reinterpret_cast<const f32x4*>(sR);
        #pragma unroll
        for (int k = 0; k < 2; ++k) {
            const int i = k * BLOCK + t;
            if (i < (3 * BLOCK) / 4)       __builtin_nontemporal_store(s4[i], vd + i);
            else if (i < (6 * BLOCK) / 4)  __builtin_nontemporal_store(s4[i], od + (i - (3 * BLOCK) / 4));
        }
    } else {
        float* vdst = out + 3 * (size_t)N + (size_t)base * 3;
        float* odst = out + 6 * (size_t)N + (size_t)base * 3;
        const int rem = (N - base) < BLOCK ? (N - base) : BLOCK;
        #pragma unroll
        for (int k = 0; k < 3; ++k) {
            int i = k * BLOCK + t;
            if (i < rem * 3) {
                __builtin_nontemporal_store(sR[i], vdst + i);
                __builtin_nontemporal_store(sR[BLOCK * 3 + i], odst + i);
            }
        }
    }
}

extern "C" void kernel_launch(void* const* d_in, const int* in_sizes, int n_in,
                              void* d_out, int out_size, void* d_ws, size_t ws_size,
                              hipStream_t stream) {
    const float* pos  = (const float*)d_in[0];   // [N,3]
    const float* rot  = (const float*)d_in[1];   // [N,9]
    const float* gpos = (const float*)d_in[2];   // [3]
    const float* grot = (const float*)d_in[3];   // [9]
    const float* wv   = (const float*)d_in[4];   // [6]
    float* out = (float*)d_out;

    const int N = in_sizes[0] / 3;
    const int blocks = (N + BLOCK - 1) / BLOCK;
    hipLaunchKernelGGL(pose_cost_kernel, dim3(blocks), dim3(BLOCK), 0, stream,
                       pos, rot, gpos, grot, wv, out, N);
}

// Round 3
// 293.696 us; speedup vs baseline: 1.0268x; 1.0268x over previous
//
#include <hip/hip_runtime.h>

// PoseCost: SE(3) log-map pose error over N = B*H poses.
// in:  pos [N,3] f32, rot [N,9] f32 (row-major 3x3), goal_pos [3], goal_rot [9], vec_weight [6]
// out: cost [N], rot_err [N], pos_err [N], v [N,3], omega [N,3]  (concat flat, f32)
//
// R3 structure: 4 poses/thread, zero LDS, zero barriers.
//  - per-thread rot/pos are contiguous -> 9+3 aligned dwordx4 loads, all issued up front
//  - 4 independent acos dependency chains per thread (ILP hides transcendental latency)
//  - all outputs packed into aligned dwordx4 stores (plain, not NT — NT regressed in R2)

#define BLOCK 256

typedef float f32x4 __attribute__((ext_vector_type(4)));

__device__ __forceinline__ void pose_one(
    const float* R, float p0, float p1, float p2,
    const float* G, float g0, float g1, float g2, const float* w,
    float& cost, float& re, float& pe,
    float& v0, float& v1, float& v2,
    float& o0, float& o1, float& o2)
{
    // d = goal_pos - p ;  t_ge = R^T d
    const float d0 = g0 - p0, d1 = g1 - p1, d2 = g2 - p2;
    const float tq0 = R[0] * d0 + R[3] * d1 + R[6] * d2;
    const float tq1 = R[1] * d0 + R[4] * d1 + R[7] * d2;
    const float tq2 = R[2] * d0 + R[5] * d1 + R[8] * d2;

    // M = R^T * G
    float M[9];
    #pragma unroll
    for (int i = 0; i < 3; ++i)
        #pragma unroll
        for (int j = 0; j < 3; ++j)
            M[i * 3 + j] = R[0 + i] * G[0 + j] + R[3 + i] * G[3 + j] + R[6 + i] * G[6 + j];

    const float tr = M[0] + M[4] + M[8];
    float cos_t = (tr - 1.0f) * 0.5f;
    cos_t = fminf(fmaxf(cos_t, -1.0f + 1e-7f), 1.0f - 1e-7f);
    const float theta = acosf(cos_t);
    // sin(acos(c)) == sqrt(1-c^2) on (0,pi); fmaf keeps the clamp-boundary value accurate
    const float sin_t = sqrtf(fmaf(-cos_t, cos_t, 1.0f));

    // vee(M - M^T)/2
    const float wv0 = 0.5f * (M[7] - M[5]);
    const float wv1 = 0.5f * (M[2] - M[6]);
    const float wv2 = 0.5f * (M[3] - M[1]);

    const bool small = theta < 1e-4f;   // dead after the clamp but preserves ref semantics
    const float th2 = theta * theta;
    const float scale = small ? (1.0f + th2 * (1.0f / 6.0f)) : (theta / sin_t);
    o0 = scale * wv0; o1 = scale * wv1; o2 = scale * wv2;

    // A = (1 - theta*sin/(2(1-cos)))/theta^2 == (1 - 0.5*scale*(1+cos))/theta^2
    const float A = small ? (1.0f / 12.0f)
                          : (1.0f - 0.5f * scale * (1.0f + cos_t)) / th2;

    // v = t - 0.5*(omega x t) + A*(omega*(omega.t) - |omega|^2 * t)
    const float cx0 = o1 * tq2 - o2 * tq1;
    const float cx1 = o2 * tq0 - o0 * tq2;
    const float cx2 = o0 * tq1 - o1 * tq0;
    const float odt = o0 * tq0 + o1 * tq1 + o2 * tq2;
    const float on2 = o0 * o0 + o1 * o1 + o2 * o2;
    v0 = tq0 - 0.5f * cx0 + A * (o0 * odt - on2 * tq0);
    v1 = tq1 - 0.5f * cx1 + A * (o1 * odt - on2 * tq1);
    v2 = tq2 - 0.5f * cx2 + A * (o2 * odt - on2 * tq2);

    const float we0 = w[0] * o0, we1 = w[1] * o1, we2 = w[2] * o2;
    const float wp0 = w[3] * v0, wp1 = w[4] * v1, wp2 = w[5] * v2;
    re = we0 * we0 + we1 * we1 + we2 * we2;
    pe = wp0 * wp0 + wp1 * wp1 + wp2 * wp2;
    re = (re < 0.0f) ? 0.0f : re;   // CONV_* = 0 exact semantics
    pe = (pe < 0.0f) ? 0.0f : pe;
    cost = 15.0f * re + 100.0f * pe;
}

__global__ __launch_bounds__(BLOCK) void pose_cost_kernel(
    const float* __restrict__ pos,
    const float* __restrict__ rot,
    const float* __restrict__ gpos,
    const float* __restrict__ grot,
    const float* __restrict__ wvec,
    float* __restrict__ out,
    int N)
{
    const size_t tid = (size_t)blockIdx.x * BLOCK + threadIdx.x;
    const size_t i0 = tid * 4;
    if (i0 >= (size_t)N) return;

    // uniform (wave-invariant) goal / weight data -> scalar loads
    float G[9], w[6];
    #pragma unroll
    for (int k = 0; k < 9; ++k) G[k] = grot[k];
    const float g0 = gpos[0], g1 = gpos[1], g2 = gpos[2];
    #pragma unroll
    for (int k = 0; k < 6; ++k) w[k] = wvec[k];

    const size_t Ns = (size_t)N;

    if (((N & 3) == 0)) {
        // ---- fast path: 4 poses, all 16B-aligned vector memory ops ----
        const f32x4* rs = reinterpret_cast<const f32x4*>(rot + i0 * 9);  // 36 floats
        const f32x4* ps = reinterpret_cast<const f32x4*>(pos + i0 * 3);  // 12 floats
        f32x4 r[9], p[3];
        #pragma unroll
        for (int k = 0; k < 9; ++k) r[k] = rs[k];
        #pragma unroll
        for (int k = 0; k < 3; ++k) p[k] = ps[k];

        // flattened constant-index access (SROA keeps everything in registers)
        #define RF(q) (r[(q) >> 2][(q) & 3])
        #define PF(q) (p[(q) >> 2][(q) & 3])

        f32x4 vcost, vre, vpe;
        f32x4 vv[3], vo[3];
        #define VV(q) (vv[(q) >> 2][(q) & 3])
        #define VO(q) (vo[(q) >> 2][(q) & 3])

        #pragma unroll
        for (int j = 0; j < 4; ++j) {
            float R[9];
            #pragma unroll
            for (int k = 0; k < 9; ++k) R[k] = RF(9 * j + k);
            const float p0 = PF(3 * j + 0);
            const float p1 = PF(3 * j + 1);
            const float p2 = PF(3 * j + 2);

            float c, re, pe, v0, v1, v2, o0, o1, o2;
            pose_one(R, p0, p1, p2, G, g0, g1, g2, w,
                     c, re, pe, v0, v1, v2, o0, o1, o2);
            vcost[j] = c; vre[j] = re; vpe[j] = pe;
            VV(3 * j + 0) = v0; VV(3 * j + 1) = v1; VV(3 * j + 2) = v2;
            VO(3 * j + 0) = o0; VO(3 * j + 1) = o1; VO(3 * j + 2) = o2;
        }
        #undef RF
        #undef PF
        #undef VV
        #undef VO

        // aligned packed stores: i0 % 4 == 0 and N % 4 == 0
        *reinterpret_cast<f32x4*>(out + i0) = vcost;
        *reinterpret_cast<f32x4*>(out + Ns + i0) = vre;
        *reinterpret_cast<f32x4*>(out + 2 * Ns + i0) = vpe;
        f32x4* vd = reinterpret_cast<f32x4*>(out + 3 * Ns + i0 * 3);
        f32x4* od = reinterpret_cast<f32x4*>(out + 6 * Ns + i0 * 3);
        #pragma unroll
        for (int k = 0; k < 3; ++k) vd[k] = vv[k];
        #pragma unroll
        for (int k = 0; k < 3; ++k) od[k] = vo[k];
    } else {
        // ---- generic scalar path (N not divisible by 4) ----
        const size_t iend = (i0 + 4 < Ns) ? (i0 + 4) : Ns;
        for (size_t i = i0; i < iend; ++i) {
            float R[9];
            #pragma unroll
            for (int k = 0; k < 9; ++k) R[k] = rot[i * 9 + k];
            const float p0 = pos[i * 3 + 0];
            const float p1 = pos[i * 3 + 1];
            const float p2 = pos[i * 3 + 2];

            float c, re, pe, v0, v1, v2, o0, o1, o2;
            pose_one(R, p0, p1, p2, G, g0, g1, g2, w,
                     c, re, pe, v0, v1, v2, o0, o1, o2);

            out[i] = c;
            out[Ns + i] = re;
            out[2 * Ns + i] = pe;
            out[3 * Ns + i * 3 + 0] = v0;
            out[3 * Ns + i * 3 + 1] = v1;
            out[3 * Ns + i * 3 + 2] = v2;
            out[6 * Ns + i * 3 + 0] = o0;
            out[6 * Ns + i * 3 + 1] = o1;
            out[6 * Ns + i * 3 + 2] = o2;
        }
    }
}

extern "C" void kernel_launch(void* const* d_in, const int* in_sizes, int n_in,
                              void* d_out, int out_size, void* d_ws, size_t ws_size,
                              hipStream_t stream) {
    const float* pos  = (const float*)d_in[0];   // [N,3]
    const float* rot  = (const float*)d_in[1];   // [N,9]
    const float* gpos = (const float*)d_in[2];   // [3]
    const float* grot = (const float*)d_in[3];   // [9]
    const float* wv   = (const float*)d_in[4];   // [6]
    float* out = (float*)d_out;

    const int N = in_sizes[0] / 3;
    const int nthreads = (N + 3) / 4;
    const int blocks = (nthreads + BLOCK - 1) / BLOCK;
    hipLaunchKernelGGL(pose_cost_kernel, dim3(blocks), dim3(BLOCK), 0, stream,
                       pos, rot, gpos, grot, wv, out, N);
}